// Round 1
// baseline (382.212 us; speedup 1.0000x reference)
//
#include <hip/hip_runtime.h>
#include <hip/hip_bf16.h>
#include <stdint.h>

#define B_ROWS 16384
#define K_DIM  2048   // IN + H
#define H_DIM  1024
#define N_DIM  4096   // 4*H

using f32x4  = __attribute__((ext_vector_type(4))) float;
using bf16x8 = __attribute__((ext_vector_type(8))) __bf16;

// RNE float -> bf16 (inputs are finite; no NaN handling needed)
__device__ __forceinline__ unsigned short f2bf(float f) {
    union { float f; unsigned u; } v; v.f = f;
    unsigned r = v.u + 0x7fffu + ((v.u >> 16) & 1u);
    return (unsigned short)(r >> 16);
}

// async global->LDS, 16B per lane. lptr must be wave-uniform (HW adds lane*16).
__device__ __forceinline__ void gload_lds16(const void* g, void* l) {
    __builtin_amdgcn_global_load_lds(
        (const __attribute__((address_space(1))) void*)g,
        (__attribute__((address_space(3))) void*)l,
        16, 0, 0);
}

__device__ __forceinline__ float rcp1p(float e) {   // 1/(1+e)
    return __builtin_amdgcn_rcpf(1.f + e);
}

// A[b][k] = bf16( k<1024 ? x[b][k] : h0[b][k-1024] )
__global__ void pack_a_kernel(const float* __restrict__ x, const float* __restrict__ h0,
                              unsigned short* __restrict__ A) {
    int tid = blockIdx.x * 256 + threadIdx.x;      // 8,388,608 threads exactly
    int64_t idx = (int64_t)tid * 4;
    int b = (int)(idx >> 11);
    int k = (int)(idx & 2047);
    const float* src = (k < 1024) ? (x + (int64_t)b * 1024 + k)
                                  : (h0 + (int64_t)b * 1024 + (k - 1024));
    float4 v = *(const float4*)src;
    ushort4 o;
    o.x = f2bf(v.x); o.y = f2bf(v.y); o.z = f2bf(v.z); o.w = f2bf(v.w);
    *(ushort4*)(A + idx) = o;
}

// Wp[r=4h+g][k] = bf16( k<1024 ? wi[g][h][k] : wh[g][h][k-1024] ); bias[r]=bi+bh
__global__ void pack_w_kernel(const float* __restrict__ wi, const float* __restrict__ wh,
                              const float* __restrict__ bi, const float* __restrict__ bh,
                              unsigned short* __restrict__ W, float* __restrict__ bias) {
    int tid = blockIdx.x * 256 + threadIdx.x;      // 2,097,152 threads exactly
    int64_t idx = (int64_t)tid * 4;
    int r = (int)(idx >> 11);
    int k = (int)(idx & 2047);
    int h = r >> 2, g = r & 3;
    const float* src = (k < 1024)
        ? (wi + (int64_t)g * 1048576 + (int64_t)h * 1024 + k)
        : (wh + (int64_t)g * 1048576 + (int64_t)h * 1024 + (k - 1024));
    float4 v = *(const float4*)src;
    ushort4 o;
    o.x = f2bf(v.x); o.y = f2bf(v.y); o.z = f2bf(v.z); o.w = f2bf(v.w);
    *(ushort4*)(W + idx) = o;
    if (k == 0) bias[r] = bi[g * 1024 + h] + bh[g * 1024 + h];
}

// 128x128 tile, BK=32, 4 waves (2x2), each wave 64x64 via 4x4 mfma 16x16x32 frags.
// W rows are gate-interleaved (r=4h+g) so the epilogue finds all 4 gates locally.
__global__ __launch_bounds__(256, 2) void lstm_gemm_fused(
    const unsigned short* __restrict__ A, const unsigned short* __restrict__ W,
    const float* __restrict__ bias, const float* __restrict__ c0,
    float* __restrict__ ht, float* __restrict__ ct)
{
    __shared__ char sm[17408];   // staging: A 8KB + W 8KB; epilogue: 4*16*68 floats

    const int t  = threadIdx.x;
    const int l  = t & 63;
    const int w  = t >> 6;
    const int wm = w >> 1, wn = w & 1;
    const int bn = blockIdx.x, bm = blockIdx.y;

    f32x4 acc[4][4];
#pragma unroll
    for (int i = 0; i < 4; ++i)
#pragma unroll
        for (int j = 0; j < 4; ++j) acc[i][j] = (f32x4){0.f, 0.f, 0.f, 0.f};

    // staging addressing: 4 threads per row of 32 bf16 (64B); issue covers 64 rows
    const int srow  = w * 16 + (l >> 2);
    const int scolb = (l & 3) * 16;
    const char* Ag = (const char*)(A + (int64_t)(bm * 128 + srow) * K_DIM) + scolb;
    const char* Wg = (const char*)(W + (int64_t)(bn * 128 + srow) * K_DIM) + scolb;
    char* AsB = sm + w * 1024;          // wave-uniform LDS dest bases
    char* WsB = sm + 8192 + w * 1024;
    const int64_t gstep = (int64_t)64 * K_DIM * 2;   // +64 rows in bytes

    // fragment read bases: lane l -> row (l&15), k-group (l>>4)*8 (16B)
    const char* ArdB = sm + (wm * 64 + (l & 15)) * 64 + (l >> 4) * 16;
    const char* WrdB = sm + 8192 + (wn * 64 + (l & 15)) * 64 + (l >> 4) * 16;

    for (int k0 = 0; k0 < K_DIM; k0 += 32) {
        const char* ag = Ag + k0 * 2;
        const char* wg = Wg + k0 * 2;
        gload_lds16(ag,         AsB);
        gload_lds16(ag + gstep, AsB + 4096);
        gload_lds16(wg,         WsB);
        gload_lds16(wg + gstep, WsB + 4096);
        __syncthreads();                 // drains vmcnt, data in LDS

        bf16x8 af[4], wf[4];
#pragma unroll
        for (int mf = 0; mf < 4; ++mf) af[mf] = *(const bf16x8*)(ArdB + mf * 1024);
#pragma unroll
        for (int nf = 0; nf < 4; ++nf) wf[nf] = *(const bf16x8*)(WrdB + nf * 1024);

#pragma unroll
        for (int mf = 0; mf < 4; ++mf)
#pragma unroll
            for (int nf = 0; nf < 4; ++nf)
                acc[mf][nf] = __builtin_amdgcn_mfma_f32_16x16x32_bf16(
                    af[mf], wf[nf], acc[mf][nf], 0, 0, 0);
        __syncthreads();                 // protect LDS before next stage
    }

    // ---- fused epilogue ----
    // per-wave LDS region: 16 rows x 64 cols fp32, padded row stride 68 floats
    float* ep = (float*)(void*)sm + w * 1088;
    const int hbase = bn * 32 + wn * 16;
    const int rbase = bm * 128 + wm * 64;

#pragma unroll
    for (int mf = 0; mf < 4; ++mf) {
        // scatter acc fragment slice (16 rows x 64 cols) to LDS
#pragma unroll
        for (int nf = 0; nf < 4; ++nf)
#pragma unroll
            for (int r = 0; r < 4; ++r)
                ep[((l >> 4) * 4 + r) * 68 + nf * 16 + (l & 15)] = acc[mf][nf][r];
        // DS ops within a wave are in-order; compiler orders MayAlias accesses.

        // gather: lane -> (row, h); cols 4h..4h+3 = gates f,i,o,g (float4)
#pragma unroll
        for (int it = 0; it < 4; ++it) {
            const int row = (l >> 4) + it * 4;
            const int hs  = l & 15;
            f32x4 z = *(const f32x4*)(ep + row * 68 + hs * 4);
            const int hg = hbase + hs;
            const float4 bz = ((const float4*)bias)[hg];
            const int brow = rbase + mf * 16 + row;

            float zf = z.x + bz.x;
            float zi = z.y + bz.y;
            float zo = z.z + bz.z;
            float zg = z.w + bz.w;

            float fg = rcp1p(__expf(-zf));                  // sigmoid
            float ig = rcp1p(__expf(-zi));
            float og = rcp1p(__expf(-zo));
            float gg = 2.f * rcp1p(__expf(-2.f * zg)) - 1.f; // tanh

            int64_t oi = (int64_t)brow * H_DIM + hg;
            float c  = fg * c0[oi] + ig * gg;
            float hh = og * (2.f * rcp1p(__expf(-2.f * c)) - 1.f);
            ct[oi] = c;
            ht[oi] = hh;
        }
    }
}

extern "C" void kernel_launch(void* const* d_in, const int* in_sizes, int n_in,
                              void* d_out, int out_size, void* d_ws, size_t ws_size,
                              hipStream_t stream) {
    const float* x  = (const float*)d_in[0];
    const float* h0 = (const float*)d_in[1];
    const float* c0 = (const float*)d_in[2];
    const float* wi = (const float*)d_in[3];
    const float* bi = (const float*)d_in[4];
    const float* wh = (const float*)d_in[5];
    const float* bh = (const float*)d_in[6];

    float* ht = (float*)d_out;
    float* ct = ht + (int64_t)B_ROWS * H_DIM;

    char* ws = (char*)d_ws;
    unsigned short* A  = (unsigned short*)ws;                       // 64 MiB
    unsigned short* Wp = (unsigned short*)(ws + (64u << 20));       // 16 MiB
    float*          bs = (float*)(ws + (80u << 20));                // 16 KiB

    pack_a_kernel<<<32768, 256, 0, stream>>>(x, h0, A);
    pack_w_kernel<<<8192, 256, 0, stream>>>(wi, wh, bi, bh, Wp, bs);

    dim3 grid(N_DIM / 128, B_ROWS / 128);
    lstm_gemm_fused<<<grid, 256, 0, stream>>>(A, Wp, bs, c0, ht, ct);
}

// Round 2
// 312.011 us; speedup vs baseline: 1.2250x; 1.2250x over previous
//
#include <hip/hip_runtime.h>
#include <hip/hip_bf16.h>
#include <stdint.h>

#define B_ROWS 16384
#define K_DIM  2048   // IN + H
#define H_DIM  1024
#define N_DIM  4096   // 4*H
#define KB     (K_DIM * 2)      // bytes per packed row (4096)
#define NT     (K_DIM / 64)     // 32 K-tiles of BK=64
#define BUFSZ  65536u           // one LDS double-buffer half (A 32K + B 32K)

using f32x4  = __attribute__((ext_vector_type(4))) float;
using bf16x8 = __attribute__((ext_vector_type(8))) __bf16;

// RNE float -> bf16 (inputs are finite)
__device__ __forceinline__ unsigned short f2bf(float f) {
    union { float f; unsigned u; } v; v.f = f;
    unsigned r = v.u + 0x7fffu + ((v.u >> 16) & 1u);
    return (unsigned short)(r >> 16);
}

// async global->LDS, 16B/lane. LDS dest must be wave-uniform (HW adds lane*16).
__device__ __forceinline__ void gload16(const void* g, const void* l) {
    __builtin_amdgcn_global_load_lds(
        (const __attribute__((address_space(1))) void*)g,
        (__attribute__((address_space(3))) void*)l,
        16, 0, 0);
}

__device__ __forceinline__ float rcp1p(float e) {   // 1/(1+e)
    return __builtin_amdgcn_rcpf(1.f + e);
}

// ---------------- pack kernels (unchanged, verified round 1) ----------------
__global__ void pack_a_kernel(const float* __restrict__ x, const float* __restrict__ h0,
                              unsigned short* __restrict__ A) {
    int tid = blockIdx.x * 256 + threadIdx.x;
    int64_t idx = (int64_t)tid * 4;
    int b = (int)(idx >> 11);
    int k = (int)(idx & 2047);
    const float* src = (k < 1024) ? (x + (int64_t)b * 1024 + k)
                                  : (h0 + (int64_t)b * 1024 + (k - 1024));
    float4 v = *(const float4*)src;
    ushort4 o;
    o.x = f2bf(v.x); o.y = f2bf(v.y); o.z = f2bf(v.z); o.w = f2bf(v.w);
    *(ushort4*)(A + idx) = o;
}

__global__ void pack_w_kernel(const float* __restrict__ wi, const float* __restrict__ wh,
                              const float* __restrict__ bi, const float* __restrict__ bh,
                              unsigned short* __restrict__ W, float* __restrict__ bias) {
    int tid = blockIdx.x * 256 + threadIdx.x;
    int64_t idx = (int64_t)tid * 4;
    int r = (int)(idx >> 11);
    int k = (int)(idx & 2047);
    int h = r >> 2, g = r & 3;
    const float* src = (k < 1024)
        ? (wi + (int64_t)g * 1048576 + (int64_t)h * 1024 + k)
        : (wh + (int64_t)g * 1048576 + (int64_t)h * 1024 + (k - 1024));
    float4 v = *(const float4*)src;
    ushort4 o;
    o.x = f2bf(v.x); o.y = f2bf(v.y); o.z = f2bf(v.z); o.w = f2bf(v.w);
    *(ushort4*)(W + idx) = o;
    if (k == 0) bias[r] = bi[g * 1024 + h] + bh[g * 1024 + h];
}

// ---------------- 256x256 8-phase GEMM + fused LSTM epilogue ----------------
// LDS per buffer: A-tile 256x64 bf16 (32K) @ +0, B-tile @ +32768.
// st_16x32 subtile layout: subtile st = (colbyte>>6)*16 + (row>>4), 1KB each;
// within: (row&15)*64 + ((colbyte&63) ^ ((row&8)<<2)).
// Staged via linear-dest global_load_lds with inverse-swizzled global source.

#define FENCE   asm volatile("" ::: "memory")
#define SCHED0  __builtin_amdgcn_sched_barrier(0)
#define BAR     __builtin_amdgcn_s_barrier()

#define PH_PRE  do { FENCE; BAR; \
                     asm volatile("s_waitcnt lgkmcnt(0)" ::: "memory"); \
                     SCHED0; __builtin_amdgcn_s_setprio(1); } while (0)
#define PH_POST do { __builtin_amdgcn_s_setprio(0); SCHED0; FENCE; BAR; } while (0)
#define PH_POST_V do { __builtin_amdgcn_s_setprio(0); SCHED0; \
                       asm volatile("s_waitcnt vmcnt(6)" ::: "memory"); \
                       SCHED0; FENCE; BAR; } while (0)

__global__ __launch_bounds__(512, 2) void lstm_gemm_fused(
    const unsigned short* __restrict__ A, const unsigned short* __restrict__ W,
    const float* __restrict__ bias, const float* __restrict__ c0,
    float* __restrict__ ht, float* __restrict__ ct)
{
    __shared__ char sm[131072];

    const int tid = threadIdx.x;
    const int l   = tid & 63;
    const int w   = tid >> 6;         // wave 0..7
    const int wm  = w >> 2;           // 0..1  (row half: 128 rows)
    const int wn  = w & 3;            // 0..3  (col quarter: 64 cols)

    // XCD-aware bijective swizzle (1024 blocks, %8==0)
    const int bid = blockIdx.x;
    const int nid = (bid & 7) * 128 + (bid >> 3);
    const int bm  = nid >> 4;         // 0..63 (M tiles)
    const int bn  = nid & 15;         // 0..15 (N tiles)

    f32x4 acc[8][4];
#pragma unroll
    for (int i = 0; i < 8; ++i)
#pragma unroll
        for (int j = 0; j < 4; ++j) acc[i][j] = (f32x4){0.f, 0.f, 0.f, 0.f};

    // ---- staging source addressing (inverse-swizzled) ----
    // chunk c (8KB, 8 subtiles): wave w writes subtile (c*8+w); lane l:
    //   row = c*128 + w*16 + (l>>2), colbyte = h*64 + (((l&3)<<4) ^ (l&32))
    const int srow = w * 16 + (l >> 2);
    const int scb  = ((l & 3) << 4) ^ (l & 32);
    const char* Asrc = (const char*)A + (size_t)(bm * 256 + srow) * KB + scb;
    const char* Wsrc = (const char*)W + (size_t)(bn * 256 + srow) * KB + scb;
    const uint32_t AstL = (uint32_t)w * 1024u;            // LDS dest lane-uniform part
    const uint32_t BstL = 32768u + (uint32_t)w * 1024u;

#define STAGE_A(TS, H, BOFF) do { \
    const char* s_ = Asrc + (size_t)(TS) * 128 + (H) * 64; \
    gload16(s_,            sm + (BOFF) + (H) * 16384u + AstL); \
    gload16(s_ + 128 * KB, sm + (BOFF) + (H) * 16384u + 8192u + AstL); \
} while (0)
#define STAGE_B(TS, H, BOFF) do { \
    const char* s_ = Wsrc + (size_t)(TS) * 128 + (H) * 64; \
    gload16(s_,            sm + (BOFF) + (H) * 16384u + BstL); \
    gload16(s_ + 128 * KB, sm + (BOFF) + (H) * 16384u + 8192u + BstL); \
} while (0)

    // ---- fragment read addressing (swizzled) ----
    // row = base + mf*16 + (l&15), colbyte = kk*64 + (l>>4)*16
    const int rr = l & 15, kg = l >> 4;
    const uint32_t loff = (uint32_t)rr * 64u + (((uint32_t)kg * 16u) ^ (uint32_t)((rr & 8) << 2));
    const uint32_t Ard = (uint32_t)(wm * 8) * 1024u + loff;            // + kk*16384 + mf*1024
    const uint32_t Brd = 32768u + (uint32_t)(wn * 4) * 1024u + loff;   // + kk*16384 + nf*1024

    bf16x8 a[8], b0, b1;

#define LOAD_A(BOFF, KK) do { \
    _Pragma("unroll") \
    for (int mf_ = 0; mf_ < 8; ++mf_) \
        a[mf_] = *(const bf16x8*)(sm + (BOFF) + (KK) * 16384u + Ard + mf_ * 1024u); \
} while (0)
#define RD_B(BOFF, KK, NF) (*(const bf16x8*)(sm + (BOFF) + (KK) * 16384u + Brd + (NF) * 1024u))
#define MM2(NF0, NF1) do { \
    _Pragma("unroll") \
    for (int mf_ = 0; mf_ < 8; ++mf_) { \
        acc[mf_][NF0] = __builtin_amdgcn_mfma_f32_16x16x32_bf16(a[mf_], b0, acc[mf_][NF0], 0, 0, 0); \
        acc[mf_][NF1] = __builtin_amdgcn_mfma_f32_16x16x32_bf16(a[mf_], b1, acc[mf_][NF1], 0, 0, 0); \
    } \
} while (0)

    // ---- prologue: tile0 fully + tile1 {A0,B0,A1}; newest-3 stay in flight ----
    STAGE_A(0, 0, 0u); STAGE_B(0, 0, 0u); STAGE_A(0, 1, 0u); STAGE_B(0, 1, 0u);
    STAGE_A(1, 0, BUFSZ); STAGE_B(1, 0, BUFSZ); STAGE_A(1, 1, BUFSZ);
    asm volatile("s_waitcnt vmcnt(6)" ::: "memory");
    SCHED0; FENCE; BAR;

    // ---- main loop: per tile 4 phases; stage map (death-driven):
    //  p0: B1(t+1)->next  p1: A0(t+2)->cur  p2: B0(t+2)->cur  p3: A1(t+2)->cur
#define DO_TILE(CUR, NXT, T) do { \
    const int tn1_ = ((T) + 1 < NT) ? (T) + 1 : NT - 1; \
    const int tn2_ = ((T) + 2 < NT) ? (T) + 2 : NT - 1; \
    /* phase 0: kk=0, nf 0,1 */ \
    LOAD_A(CUR, 0); \
    b0 = RD_B(CUR, 0, 0); b1 = RD_B(CUR, 0, 1); \
    STAGE_B(tn1_, 1, NXT); \
    PH_PRE; MM2(0, 1); PH_POST; \
    /* phase 1: kk=0, nf 2,3 */ \
    b0 = RD_B(CUR, 0, 2); b1 = RD_B(CUR, 0, 3); \
    STAGE_A(tn2_, 0, CUR); \
    PH_PRE; MM2(2, 3); PH_POST; \
    /* phase 2: kk=1, nf 0,1 */ \
    LOAD_A(CUR, 1); \
    b0 = RD_B(CUR, 1, 0); b1 = RD_B(CUR, 1, 1); \
    STAGE_B(tn2_, 0, CUR); \
    PH_PRE; MM2(0, 1); PH_POST; \
    /* phase 3: kk=1, nf 2,3 */ \
    b0 = RD_B(CUR, 1, 2); b1 = RD_B(CUR, 1, 3); \
    STAGE_A(tn2_, 1, CUR); \
    PH_PRE; MM2(2, 3); PH_POST_V; \
} while (0)

#pragma unroll 1
    for (int tt = 0; tt < NT; tt += 2) {
        DO_TILE(0u, BUFSZ, tt);
        DO_TILE(BUFSZ, 0u, tt + 1);
    }

    // ---- fused LSTM epilogue ----
    asm volatile("s_waitcnt vmcnt(0)" ::: "memory");
    FENCE; BAR;

    float* ep = (float*)(void*)sm + w * 1088;   // 16 rows x 68 floats per wave
    const int hbase = bn * 64 + wn * 16;
    const int rbase = bm * 256 + wm * 128;

#pragma unroll
    for (int mf = 0; mf < 8; ++mf) {
#pragma unroll
        for (int nf = 0; nf < 4; ++nf)
#pragma unroll
            for (int r = 0; r < 4; ++r)
                ep[((l >> 4) * 4 + r) * 68 + nf * 16 + (l & 15)] = acc[mf][nf][r];

#pragma unroll
        for (int it = 0; it < 4; ++it) {
            const int row = (l >> 4) + it * 4;
            const int hs  = l & 15;
            f32x4 z = *(const f32x4*)(ep + row * 68 + hs * 4);
            const int hg = hbase + hs;
            const float4 bz = ((const float4*)bias)[hg];
            const int brow = rbase + mf * 16 + row;

            float zf = z.x + bz.x;
            float zi = z.y + bz.y;
            float zo = z.z + bz.z;
            float zg = z.w + bz.w;

            float fg = rcp1p(__expf(-zf));                   // sigmoid
            float ig = rcp1p(__expf(-zi));
            float og = rcp1p(__expf(-zo));
            float gg = 2.f * rcp1p(__expf(-2.f * zg)) - 1.f; // tanh

            int64_t oi = (int64_t)brow * H_DIM + hg;
            float c  = fg * c0[oi] + ig * gg;
            float hh = og * (2.f * rcp1p(__expf(-2.f * c)) - 1.f);
            ct[oi] = c;
            ht[oi] = hh;
        }
    }
}

extern "C" void kernel_launch(void* const* d_in, const int* in_sizes, int n_in,
                              void* d_out, int out_size, void* d_ws, size_t ws_size,
                              hipStream_t stream) {
    const float* x  = (const float*)d_in[0];
    const float* h0 = (const float*)d_in[1];
    const float* c0 = (const float*)d_in[2];
    const float* wi = (const float*)d_in[3];
    const float* bi = (const float*)d_in[4];
    const float* wh = (const float*)d_in[5];
    const float* bh = (const float*)d_in[6];

    float* ht = (float*)d_out;
    float* ct = ht + (int64_t)B_ROWS * H_DIM;

    char* ws = (char*)d_ws;
    unsigned short* A  = (unsigned short*)ws;                       // 64 MiB
    unsigned short* Wp = (unsigned short*)(ws + (64u << 20));       // 16 MiB
    float*          bs = (float*)(ws + (80u << 20));                // 16 KiB

    pack_a_kernel<<<32768, 256, 0, stream>>>(x, h0, A);
    pack_w_kernel<<<8192, 256, 0, stream>>>(wi, wh, bi, bh, Wp, bs);

    lstm_gemm_fused<<<1024, 512, 0, stream>>>(A, Wp, bs, c0, ht, ct);
}